// Round 6
// baseline (318.661 us; speedup 1.0000x reference)
//
#include <hip/hip_runtime.h>

// out = LIF16(x @ W^T + b), x:[32768,512] f32, W:[512,512] f32, b:[512] f32.
//
// CORRECTNESS INVARIANT (rounds 0-4; do not break):
// Reference cur = SINGLE sequential ascending-k fp32 FMA chain (one
// accumulator per C element, k=0..511 ascending), then ONE bias add; LIF in
// fp32 RN, source identical to the round-3/4 passing kernels (absmax 0.0).
// K-splits / reassociation forbidden. v_pk_fma packs two *different* C
// elements per instruction - per-chain rounding intact.
//
// Round-5 lesson: a 4-way simultaneous rewrite (dbuf+lambda+new staging+new
// micro-tile) produced structural wrongness we could not bisect. This round
// is the verified round-4 kernel with ONE mechanical change: BM 128->256,
// micro-tile 8x8 -> 16x8 (A-side code paths literally duplicated at +128
// rows). Theory: round 4 was LDS-read-pipe-bound (1.0 B/FMA demanded ~128
// B/cyc/CU vs ~110 effective; VALUBusy 55% matches the 2x oversubscription).
// 16x8 cuts LDS reads to 0.75 B/FMA -> FMA-wall-bound (~109 us floor).

typedef float v2f __attribute__((ext_vector_type(2)));
typedef float v4f __attribute__((ext_vector_type(4)));

#define BM 256
#define BN 128
#define BK 16
#define LDA (BM + 4)   // 260: rows 16B-aligned, staging/frag reads bank-clean
#define LDB (BN + 4)   // 132

__global__ __launch_bounds__(256, 2)
void lif_gemm_f32(const float* __restrict__ x,    // [B, K]
                  const float* __restrict__ W,    // [H, K]
                  const float* __restrict__ bias, // [H]
                  float* __restrict__ out,        // [B, H]
                  int K, int H)
{
    __shared__ __align__(16) float As[BK][LDA];   // k-major: As[k][m], m in [0,256)
    __shared__ __align__(16) float Bs[BK][LDB];   // k-major: Bs[k][n], n in [0,128)

    const int tid = threadIdx.x;
    const int tm  = tid & 15;        // rows tm*4 + {0,64,128,192} blocks
    const int tn  = tid >> 4;        // cols tn*4 and 64+tn*4
    const int n0  = blockIdx.x * BN; // N fastest: consecutive blocks share A
    const int m0  = blockIdx.y * BM;

    // Staging (round-4 idiom): each thread covers row ra (and ra+128 for A)
    // at k-half kc. A: 256 rows x 16 k -> 16 floats/thread (4 v4f).
    // B: 128 rows x 16 k -> 8 floats/thread (2 v4f).
    const int ra = tid >> 1;         // 0..127
    const int kc = (tid & 1) << 3;   // 0 or 8

    const float* xg  = x + (size_t)(m0 + ra) * K + kc;
    const float* xg2 = xg + (size_t)128 * K;             // rows +128
    const float* wg  = W + (size_t)(n0 + ra) * K + kc;

    v2f acc[16][4];                  // 16 rows x 8 cols (4 v2f pairs)
#pragma unroll
    for (int i = 0; i < 16; ++i)
#pragma unroll
        for (int j = 0; j < 4; ++j)
            acc[i][j] = (v2f){0.0f, 0.0f};

    // prefetch tile 0 into registers
    v4f a0 = *(const v4f*)(xg);
    v4f a1 = *(const v4f*)(xg + 4);
    v4f a2 = *(const v4f*)(xg2);
    v4f a3 = *(const v4f*)(xg2 + 4);
    v4f b0 = *(const v4f*)(wg);
    v4f b1 = *(const v4f*)(wg + 4);

    for (int k0 = 0; k0 < K; k0 += BK) {
        __syncthreads();             // previous iteration's LDS reads done

        // transpose-stage registers -> LDS
#pragma unroll
        for (int i = 0; i < 4; ++i) {
            As[kc + i][ra]           = a0[i];
            As[kc + 4 + i][ra]       = a1[i];
            As[kc + i][128 + ra]     = a2[i];
            As[kc + 4 + i][128 + ra] = a3[i];
            Bs[kc + i][ra]           = b0[i];
            Bs[kc + 4 + i][ra]       = b1[i];
        }
        __syncthreads();

        // issue next tile's global loads (whole compute section to land)
        const int kn = (k0 + BK < K) ? (k0 + BK) : k0;  // tail: harmless reload
        a0 = *(const v4f*)(xg + kn);
        a1 = *(const v4f*)(xg + kn + 4);
        a2 = *(const v4f*)(xg2 + kn);
        a3 = *(const v4f*)(xg2 + kn + 4);
        b0 = *(const v4f*)(wg + kn);
        b1 = *(const v4f*)(wg + kn + 4);

#pragma unroll
        for (int k = 0; k < BK; ++k) {   // ascending k: order is load-bearing
            const v4f af0 = *(const v4f*)&As[k][tm * 4];
            const v4f af1 = *(const v4f*)&As[k][64 + tm * 4];
            const v4f af2 = *(const v4f*)&As[k][128 + tm * 4];
            const v4f af3 = *(const v4f*)&As[k][192 + tm * 4];
            const v4f blo = *(const v4f*)&Bs[k][tn * 4];
            const v4f bhi = *(const v4f*)&Bs[k][64 + tn * 4];

            const v2f bb[4] = { (v2f){blo[0], blo[1]}, (v2f){blo[2], blo[3]},
                                (v2f){bhi[0], bhi[1]}, (v2f){bhi[2], bhi[3]} };
            const float av[16] = { af0[0], af0[1], af0[2], af0[3],
                                   af1[0], af1[1], af1[2], af1[3],
                                   af2[0], af2[1], af2[2], af2[3],
                                   af3[0], af3[1], af3[2], af3[3] };
#pragma unroll
            for (int i = 0; i < 16; ++i) {
                const v2f a2v = (v2f){av[i], av[i]};
#pragma unroll
                for (int j = 0; j < 4; ++j)
                    acc[i][j] = __builtin_elementwise_fma(a2v, bb[j], acc[i][j]);
            }
        }
    }

    // Epilogue: + bias (single fp32 add), 16-step fp32 LIF (identical source
    // to the round-3/4 passing kernels), store count/16.
    float bcol[8];
#pragma unroll
    for (int j = 0; j < 8; ++j) {
        const int col = (j < 4) ? (tn * 4 + j) : (64 + tn * 4 + (j - 4));
        bcol[j] = bias[n0 + col];
    }

#pragma unroll
    for (int i = 0; i < 16; ++i) {
        // av[i] row layout: i=0..3 -> tm*4+i; 4..7 -> 64+...; 8..11 -> 128+...;
        // 12..15 -> 192+...
        const int row = m0 + 64 * (i >> 2) + tm * 4 + (i & 3);
        float res[8];
#pragma unroll
        for (int j = 0; j < 8; ++j) {
            const float cur = acc[i][j >> 1][j & 1] + bcol[j];
            float v = 0.0f;
            int cnt = 0;
#pragma unroll
            for (int t = 0; t < 16; ++t) {
                v = v + (cur - v) * 0.5f;    // == v + (cur - v)/2, RN-identical
                const bool s = (v >= 1.0f);  // == (v - 1.0f) >= 0 in fp32
                cnt += s ? 1 : 0;
                v = s ? 0.0f : v;
            }
            res[j] = (float)cnt * 0.0625f;   // exact multiple of 1/16
        }
        float* op = out + (size_t)row * H + n0;
        *(v4f*)(op + tn * 4)      = (v4f){res[0], res[1], res[2], res[3]};
        *(v4f*)(op + 64 + tn * 4) = (v4f){res[4], res[5], res[6], res[7]};
    }
}

extern "C" void kernel_launch(void* const* d_in, const int* in_sizes, int n_in,
                              void* d_out, int out_size, void* d_ws, size_t ws_size,
                              hipStream_t stream) {
    const float* x    = (const float*)d_in[0];
    const float* W    = (const float*)d_in[1];
    const float* bias = (const float*)d_in[2];
    float* out = (float*)d_out;

    const int K = 512;
    const int H = 512;
    const int B = in_sizes[0] / K;   // 32768

    dim3 grid(H / BN, B / BM);       // (4, 128) = 512 blocks = 2/CU exactly
    dim3 block(256);
    lif_gemm_f32<<<grid, block, 0, stream>>>(x, W, bias, out, K, H);
}

// Round 7
// 315.301 us; speedup vs baseline: 1.0107x; 1.0107x over previous
//
#include <hip/hip_runtime.h>

// out = LIF16(x @ W^T + b), x:[32768,512] f32, W:[512,512] f32, b:[512] f32.
//
// CORRECTNESS INVARIANT (rounds 0-6; do not break):
// Reference cur = SINGLE sequential ascending-k fp32 FMA chain (one
// accumulator per C element, k=0..511 ascending), then ONE bias add; LIF in
// fp32 RN, source identical to round-3/4/6 passing kernels (absmax 0.0).
// K-splits / reassociation forbidden. v_pk_fma packs two *different* C
// elements per instruction - per-chain rounding intact.
//
// Round-7 change (single delta from verified round-6 base): LDS double
// buffering, one barrier per iteration (was two). Body order:
//   [stage tile t -> buf pp; sync; prefetch t+1 -> regs; compute buf pp]
// Safety: passing sync_t implies all waves finished compute_{t-1} (program
// order), and stage_{t+1} writes buf p_{t-1} whose last readers were
// compute_{t-1}. Theory: round-6's 33% VALU idle = LDS-pipe oversubscription
// (~26%) + 2-barrier rendezvous with only 2 waves/SIMD; halving barriers and
// overlapping stage with compute recovers most of the barrier share.

typedef float v2f __attribute__((ext_vector_type(2)));
typedef float v4f __attribute__((ext_vector_type(4)));

#define BM 256
#define BN 128
#define BK 16
#define LDA (BM + 4)   // 260: rows 16B-aligned, staging/frag reads bank-clean
#define LDB (BN + 4)   // 132

__global__ __launch_bounds__(256, 2)
void lif_gemm_f32(const float* __restrict__ x,    // [B, K]
                  const float* __restrict__ W,    // [H, K]
                  const float* __restrict__ bias, // [H]
                  float* __restrict__ out,        // [B, H]
                  int K, int H)
{
    __shared__ __align__(16) float As[2][BK][LDA];   // k-major: As[p][k][m]
    __shared__ __align__(16) float Bs[2][BK][LDB];   // k-major: Bs[p][k][n]

    const int tid = threadIdx.x;
    const int tm  = tid & 15;        // rows tm*4 + {0,64,128,192}
    const int tn  = tid >> 4;        // cols tn*4 and 64+tn*4
    const int n0  = blockIdx.x * BN; // N fastest: consecutive blocks share A
    const int m0  = blockIdx.y * BM;

    // Staging (round-4/6 idiom): thread covers rows ra / ra+128 at k-half kc.
    const int ra = tid >> 1;         // 0..127
    const int kc = (tid & 1) << 3;   // 0 or 8

    const float* xg  = x + (size_t)(m0 + ra) * K + kc;
    const float* xg2 = xg + (size_t)128 * K;             // rows +128
    const float* wg  = W + (size_t)(n0 + ra) * K + kc;

    v2f acc[16][4];                  // 16 rows x 8 cols (4 v2f pairs)
#pragma unroll
    for (int i = 0; i < 16; ++i)
#pragma unroll
        for (int j = 0; j < 4; ++j)
            acc[i][j] = (v2f){0.0f, 0.0f};

    // prefetch tile 0 into registers
    v4f a0 = *(const v4f*)(xg);
    v4f a1 = *(const v4f*)(xg + 4);
    v4f a2 = *(const v4f*)(xg2);
    v4f a3 = *(const v4f*)(xg2 + 4);
    v4f b0 = *(const v4f*)(wg);
    v4f b1 = *(const v4f*)(wg + 4);

    int pp = 0;
    for (int k0 = 0; k0 < K; k0 += BK) {
        float (*Asp)[LDA] = As[pp];
        float (*Bsp)[LDB] = Bs[pp];

        // stage tile k0 (held in regs) -> LDS buf pp
#pragma unroll
        for (int i = 0; i < 4; ++i) {
            Asp[kc + i][ra]           = a0[i];
            Asp[kc + 4 + i][ra]       = a1[i];
            Asp[kc + i][128 + ra]     = a2[i];
            Asp[kc + 4 + i][128 + ra] = a3[i];
            Bsp[kc + i][ra]           = b0[i];
            Bsp[kc + 4 + i][ra]       = b1[i];
        }
        __syncthreads();             // single barrier per iteration

        // prefetch tile k0+BK (whole compute section to land)
        const int kn = (k0 + BK < K) ? (k0 + BK) : k0;  // tail: harmless reload
        a0 = *(const v4f*)(xg + kn);
        a1 = *(const v4f*)(xg + kn + 4);
        a2 = *(const v4f*)(xg2 + kn);
        a3 = *(const v4f*)(xg2 + kn + 4);
        b0 = *(const v4f*)(wg + kn);
        b1 = *(const v4f*)(wg + kn + 4);

#pragma unroll
        for (int k = 0; k < BK; ++k) {   // ascending k: order is load-bearing
            const v4f af0 = *(const v4f*)&Asp[k][tm * 4];
            const v4f af1 = *(const v4f*)&Asp[k][64 + tm * 4];
            const v4f af2 = *(const v4f*)&Asp[k][128 + tm * 4];
            const v4f af3 = *(const v4f*)&Asp[k][192 + tm * 4];
            const v4f blo = *(const v4f*)&Bsp[k][tn * 4];
            const v4f bhi = *(const v4f*)&Bsp[k][64 + tn * 4];

            const v2f bb[4] = { (v2f){blo[0], blo[1]}, (v2f){blo[2], blo[3]},
                                (v2f){bhi[0], bhi[1]}, (v2f){bhi[2], bhi[3]} };
            const float av[16] = { af0[0], af0[1], af0[2], af0[3],
                                   af1[0], af1[1], af1[2], af1[3],
                                   af2[0], af2[1], af2[2], af2[3],
                                   af3[0], af3[1], af3[2], af3[3] };
#pragma unroll
            for (int i = 0; i < 16; ++i) {
                const v2f a2v = (v2f){av[i], av[i]};
#pragma unroll
                for (int j = 0; j < 4; ++j)
                    acc[i][j] = __builtin_elementwise_fma(a2v, bb[j], acc[i][j]);
            }
        }
        pp ^= 1;
    }

    // Epilogue: + bias (single fp32 add), 16-step fp32 LIF (identical source
    // to the round-3/4/6 passing kernels), store count/16.
    float bcol[8];
#pragma unroll
    for (int j = 0; j < 8; ++j) {
        const int col = (j < 4) ? (tn * 4 + j) : (64 + tn * 4 + (j - 4));
        bcol[j] = bias[n0 + col];
    }

#pragma unroll
    for (int i = 0; i < 16; ++i) {
        const int row = m0 + 64 * (i >> 2) + tm * 4 + (i & 3);
        float res[8];
#pragma unroll
        for (int j = 0; j < 8; ++j) {
            const float cur = acc[i][j >> 1][j & 1] + bcol[j];
            float v = 0.0f;
            int cnt = 0;
#pragma unroll
            for (int t = 0; t < 16; ++t) {
                v = v + (cur - v) * 0.5f;    // == v + (cur - v)/2, RN-identical
                const bool s = (v >= 1.0f);  // == (v - 1.0f) >= 0 in fp32
                cnt += s ? 1 : 0;
                v = s ? 0.0f : v;
            }
            res[j] = (float)cnt * 0.0625f;   // exact multiple of 1/16
        }
        float* op = out + (size_t)row * H + n0;
        *(v4f*)(op + tn * 4)      = (v4f){res[0], res[1], res[2], res[3]};
        *(v4f*)(op + 64 + tn * 4) = (v4f){res[4], res[5], res[6], res[7]};
    }
}

extern "C" void kernel_launch(void* const* d_in, const int* in_sizes, int n_in,
                              void* d_out, int out_size, void* d_ws, size_t ws_size,
                              hipStream_t stream) {
    const float* x    = (const float*)d_in[0];
    const float* W    = (const float*)d_in[1];
    const float* bias = (const float*)d_in[2];
    float* out = (float*)d_out;

    const int K = 512;
    const int H = 512;
    const int B = in_sizes[0] / K;   // 32768

    dim3 grid(H / BN, B / BM);       // (4, 128) = 512 blocks = 2/CU exactly
    dim3 block(256);
    lif_gemm_f32<<<grid, block, 0, stream>>>(x, W, bias, out, K, H);
}

// Round 8
// 308.004 us; speedup vs baseline: 1.0346x; 1.0237x over previous
//
#include <hip/hip_runtime.h>

// out = LIF16(x @ W^T + b), x:[32768,512] f32, W:[512,512] f32, b:[512] f32.
//
// CORRECTNESS INVARIANT (rounds 0-7; do not break):
// Reference cur = SINGLE sequential ascending-k fp32 FMA chain (one
// accumulator per C element, k=0..511 ascending), then ONE bias add; LIF in
// fp32 RN, source identical to round-3/4/6/7 passing kernels (absmax 0.0).
// K-splits / reassociation forbidden.
//
// Round-8 theory: R7 counters show 142K cyc/CU of non-FMA VALU (404K busy vs
// 262K FMA floor) and LDS pipe only ~50% utilized -> the limiter is operand
// marshalling (v_pk_fma pair alignment + (v2f){a,a} broadcasts + possible
// AGPR<->VGPR copies; VGPR_Count=88 < 128 live accs implies AGPR use), not
// LDS bandwidth, not barriers (dbuf was neutral). Change: scalar v_fma_f32
// with direct vector-element operands (zero marshalling — v_fma can read any
// VGPR), float accumulators, explicit fragment double-buffer across k.
// Same issue-rate ceiling as pk (157.3 TF fp32 either way), fewer movs.

typedef float v4f __attribute__((ext_vector_type(4)));

#define BM 256
#define BN 128
#define BK 16
#define LDA (BM + 4)   // 260
#define LDB (BN + 4)   // 132

__global__ __launch_bounds__(256, 2)
void lif_gemm_f32(const float* __restrict__ x,    // [B, K]
                  const float* __restrict__ W,    // [H, K]
                  const float* __restrict__ bias, // [H]
                  float* __restrict__ out,        // [B, H]
                  int K, int H)
{
    __shared__ __align__(16) float As[2][BK][LDA];   // k-major: As[p][k][m]
    __shared__ __align__(16) float Bs[2][BK][LDB];   // k-major: Bs[p][k][n]

    const int tid = threadIdx.x;
    const int tm  = tid & 15;        // rows tm*4 + {0,64,128,192}
    const int tn  = tid >> 4;        // cols tn*4 and 64+tn*4
    const int n0  = blockIdx.x * BN;
    const int m0  = blockIdx.y * BM;

    const int ra = tid >> 1;         // 0..127
    const int kc = (tid & 1) << 3;   // 0 or 8

    const float* xg  = x + (size_t)(m0 + ra) * K + kc;
    const float* xg2 = xg + (size_t)128 * K;
    const float* wg  = W + (size_t)(n0 + ra) * K + kc;

    float acc[16][8];                // plain scalars: no pair constraints
#pragma unroll
    for (int i = 0; i < 16; ++i)
#pragma unroll
        for (int j = 0; j < 8; ++j)
            acc[i][j] = 0.0f;

    // prefetch tile 0 into registers
    v4f a0 = *(const v4f*)(xg);
    v4f a1 = *(const v4f*)(xg + 4);
    v4f a2 = *(const v4f*)(xg2);
    v4f a3 = *(const v4f*)(xg2 + 4);
    v4f b0 = *(const v4f*)(wg);
    v4f b1 = *(const v4f*)(wg + 4);

    int pp = 0;
    for (int k0 = 0; k0 < K; k0 += BK) {
        float (*Asp)[LDA] = As[pp];
        float (*Bsp)[LDB] = Bs[pp];

        // stage tile k0 (held in regs) -> LDS buf pp
#pragma unroll
        for (int i = 0; i < 4; ++i) {
            Asp[kc + i][ra]           = a0[i];
            Asp[kc + 4 + i][ra]       = a1[i];
            Asp[kc + i][128 + ra]     = a2[i];
            Asp[kc + 4 + i][128 + ra] = a3[i];
            Bsp[kc + i][ra]           = b0[i];
            Bsp[kc + 4 + i][ra]       = b1[i];
        }
        __syncthreads();             // single barrier per iteration

        // prefetch tile k0+BK (whole compute section to land)
        const int kn = (k0 + BK < K) ? (k0 + BK) : k0;  // tail: harmless reload
        a0 = *(const v4f*)(xg + kn);
        a1 = *(const v4f*)(xg + kn + 4);
        a2 = *(const v4f*)(xg2 + kn);
        a3 = *(const v4f*)(xg2 + kn + 4);
        b0 = *(const v4f*)(wg + kn);
        b1 = *(const v4f*)(wg + kn + 4);

        // fragment regs, double-buffered across k (reads issue one k early)
        v4f fa0[2], fa1[2], fa2[2], fa3[2], fb0[2], fb1[2];
        fa0[0] = *(const v4f*)&Asp[0][tm * 4];
        fa1[0] = *(const v4f*)&Asp[0][64 + tm * 4];
        fa2[0] = *(const v4f*)&Asp[0][128 + tm * 4];
        fa3[0] = *(const v4f*)&Asp[0][192 + tm * 4];
        fb0[0] = *(const v4f*)&Bsp[0][tn * 4];
        fb1[0] = *(const v4f*)&Bsp[0][64 + tn * 4];

#pragma unroll
        for (int k = 0; k < BK; ++k) {   // ascending k: order is load-bearing
            const int cb = k & 1, nb = cb ^ 1;
            if (k + 1 < BK) {
                fa0[nb] = *(const v4f*)&Asp[k + 1][tm * 4];
                fa1[nb] = *(const v4f*)&Asp[k + 1][64 + tm * 4];
                fa2[nb] = *(const v4f*)&Asp[k + 1][128 + tm * 4];
                fa3[nb] = *(const v4f*)&Asp[k + 1][192 + tm * 4];
                fb0[nb] = *(const v4f*)&Bsp[k + 1][tn * 4];
                fb1[nb] = *(const v4f*)&Bsp[k + 1][64 + tn * 4];
            }
            // 128 scalar v_fma_f32, operands indexed directly from frag regs
#pragma unroll
            for (int i = 0; i < 16; ++i) {
                const float a = (i < 4) ? fa0[cb][i]
                              : (i < 8) ? fa1[cb][i - 4]
                              : (i < 12) ? fa2[cb][i - 8]
                              : fa3[cb][i - 12];
#pragma unroll
                for (int j = 0; j < 8; ++j) {
                    const float b = (j < 4) ? fb0[cb][j] : fb1[cb][j - 4];
                    acc[i][j] = fmaf(a, b, acc[i][j]);
                }
            }
        }
        pp ^= 1;
    }

    // Epilogue: + bias (single fp32 add), 16-step fp32 LIF (identical source
    // to the round-3/4/6/7 passing kernels), store count/16.
    float bcol[8];
#pragma unroll
    for (int j = 0; j < 8; ++j) {
        const int col = (j < 4) ? (tn * 4 + j) : (64 + tn * 4 + (j - 4));
        bcol[j] = bias[n0 + col];
    }

#pragma unroll
    for (int i = 0; i < 16; ++i) {
        const int row = m0 + 64 * (i >> 2) + tm * 4 + (i & 3);
        float res[8];
#pragma unroll
        for (int j = 0; j < 8; ++j) {
            const float cur = acc[i][j] + bcol[j];
            float v = 0.0f;
            int cnt = 0;
#pragma unroll
            for (int t = 0; t < 16; ++t) {
                v = v + (cur - v) * 0.5f;    // == v + (cur - v)/2, RN-identical
                const bool s = (v >= 1.0f);  // == (v - 1.0f) >= 0 in fp32
                cnt += s ? 1 : 0;
                v = s ? 0.0f : v;
            }
            res[j] = (float)cnt * 0.0625f;   // exact multiple of 1/16
        }
        float* op = out + (size_t)row * H + n0;
        *(v4f*)(op + tn * 4)      = (v4f){res[0], res[1], res[2], res[3]};
        *(v4f*)(op + 64 + tn * 4) = (v4f){res[4], res[5], res[6], res[7]};
    }
}

extern "C" void kernel_launch(void* const* d_in, const int* in_sizes, int n_in,
                              void* d_out, int out_size, void* d_ws, size_t ws_size,
                              hipStream_t stream) {
    const float* x    = (const float*)d_in[0];
    const float* W    = (const float*)d_in[1];
    const float* bias = (const float*)d_in[2];
    float* out = (float*)d_out;

    const int K = 512;
    const int H = 512;
    const int B = in_sizes[0] / K;   // 32768

    dim3 grid(H / BN, B / BM);       // (4, 128) = 512 blocks = 2/CU exactly
    dim3 block(256);
    lif_gemm_f32<<<grid, block, 0, stream>>>(x, W, bias, out, K, H);
}